// Round 17
// baseline (70.734 us; speedup 1.0000x reference)
//
#include <hip/hip_runtime.h>

typedef _Float16 half8  __attribute__((ext_vector_type(8)));
typedef __fp16   fp16x2 __attribute__((ext_vector_type(2)));
typedef float    float4_t __attribute__((ext_vector_type(4)));
typedef float    float2_t __attribute__((ext_vector_type(2)));

#define SH 4
#define SW 160
#define CW (SW + 2)   // 162 staged cv cols
#define NR (SH + 2)   // 6 staged rows
#define DW (CW + 1)   // 163: depth LDS row stride

// VALU-pipe rotate-reduce within each 16-lane row: v += dpp_ror<N>(v)
template <int CTRL>
__device__ __forceinline__ float rr_add(float v) {
    const int i = __float_as_int(v);
    const int p = __builtin_amdgcn_update_dpp(i, i, CTRL, 0xF, 0xF, false);
    return v + __int_as_float(p);
}
#define ROR4 0x124
#define ROR8 0x128

__global__ __launch_bounds__(256, 4) void depth_up_fused(
    const float* __restrict__ depth,
    const float* __restrict__ cv,
    const float* __restrict__ w1,   // [8,8,3,3]
    const float* __restrict__ b1,   // [8]
    const float* __restrict__ w2,   // [36,8]
    const float* __restrict__ b2,   // [36]
    float* __restrict__ out)        // [N, 1024, 1280]
{
    const int H = 512, W = 640;
    const size_t HW = (size_t)H * W;
    const int n  = blockIdx.z;
    const int h0 = blockIdx.y * SH;
    const int cb = blockIdx.x * SW;
    const int tid  = threadIdx.x;
    const int lane = tid & 63;
    const int wv   = tid >> 6;       // wave = row within strip
    const int o    = lane & 15;
    const int krow = lane >> 4;
    const int u    = o >> 2;         // tap-group
    const int q    = o & 3;          // softmax column

    __shared__ half8 s_cv[NR * CW];  // 15,552 B
    __shared__ float s_d[NR * DW];   //  3,912 B

    const float* __restrict__ cvn = cv + (size_t)n * 8 * HW;
    const float* __restrict__ dn  = depth + (size_t)n * HW;

    // ---- stage cv (fp16x8) + depth: branchless, 972 items padded to 1024 ----
    #pragma unroll
    for (int j = 0; j < 4; ++j) {
        const int i0 = tid + 256 * j;
        const int it = i0 < (NR * CW - 1) ? i0 : (NR * CW - 1);
        const int r  = it / CW;
        const int c  = it - r * CW;
        const int gh = h0 + r - 1;
        const int gw = cb + c - 1;
        const int ghs = gh < 0 ? 0 : (gh > H - 1 ? H - 1 : gh);
        const int gws = gw < 0 ? 0 : (gw > W - 1 ? W - 1 : gw);
        const bool ok = (gh == ghs) & (gw == gws);
        const float* p = cvn + (size_t)ghs * W + gws;
        float f[9];
        #pragma unroll
        for (int ch = 0; ch < 8; ++ch) f[ch] = p[(size_t)ch * HW];
        f[8] = dn[(size_t)ghs * W + gws];
        #pragma unroll
        for (int k = 0; k < 9; ++k) f[k] = ok ? f[k] : 0.0f;
        union { half8 v8; fp16x2 h2[4]; } hu;
        #pragma unroll
        for (int pq = 0; pq < 4; ++pq)
            hu.h2[pq] = __builtin_amdgcn_cvt_pkrtz(f[2 * pq], f[2 * pq + 1]);
        s_cv[r * CW + c] = hu.v8;
        s_d[r * DW + c]  = f[8];
    }

    // ---- conv1 weights as A-fragments: A1[row=och][k], k = tap*8 + c ----
    half8 a1[3];
    #pragma unroll
    for (int ki = 0; ki < 3; ++ki) {
        const int tap = 4 * ki + krow;
        #pragma unroll
        for (int j = 0; j < 8; ++j)
            a1[ki][j] = (tap < 9 && o < 8) ? (_Float16)w1[(o * 8 + j) * 9 + tap]
                                           : (_Float16)0.0f;
    }
    int aoff[3];
    #pragma unroll
    for (int ki = 0; ki < 3; ++ki) {
        const int tap0 = 4 * ki + krow;
        const int tap  = tap0 > 8 ? 8 : tap0;
        const int ky   = tap / 3;
        const int kx   = tap - 3 * ky;
        aoff[ki] = ((wv + ky) * CW + o + kx) * 16;
    }
    const float4_t b1q = *reinterpret_cast<const float4_t*>(b1 + (krow & 1) * 4);

    half8 b2f[3] = {};
    if (krow == 0) {
        #pragma unroll
        for (int t = 0; t < 3; ++t) {
            const int m = (o + 16 * t) > 35 ? 35 : (o + 16 * t);
            const float4_t wlo = *reinterpret_cast<const float4_t*>(w2 + m * 8);
            const float4_t whi = *reinterpret_cast<const float4_t*>(w2 + m * 8 + 4);
            #pragma unroll
            for (int j = 0; j < 4; ++j) {
                b2f[t][j]     = (_Float16)wlo[j];
                b2f[t][4 + j] = (_Float16)whi[j];
            }
        }
    }
    const float C = 0.25f * 1.44269504f;
    float b2q[3];
    #pragma unroll
    for (int t = 0; t < 3; ++t) {
        const int m = (o + 16 * t) > 35 ? 35 : (o + 16 * t);
        b2q[t] = C * b2[m];
    }
    if (u != 0) b2q[2] = -1.0e38f;   // exp2 -> 0 for the invalid tap

    int poff[3];
    {
        const int taps[3] = {u, u + 4, 8};
        #pragma unroll
        for (int t = 0; t < 3; ++t) {
            const int ky = taps[t] / 3;
            const int kx = taps[t] - 3 * ky;
            poff[t] = ((wv + ky) * DW + kx) * 4;
        }
    }

    __syncthreads();

    const char* cvb = (const char*)s_cv;
    const char* sdb = (const char*)s_d;
    const float4_t zero4 = {0.0f, 0.0f, 0.0f, 0.0f};

    const half8* bb0 = (const half8*)(cvb + aoff[0]);
    const half8* bb1 = (const half8*)(cvb + aoff[1]);
    const half8* bb2 = (const half8*)(cvb + aoff[2]);
    const float* pb0 = (const float*)(sdb + poff[0] + krow * 16);
    const float* pb1 = (const float*)(sdb + poff[1] + krow * 16);
    const float* pb2 = (const float*)(sdb + poff[2] + krow * 16);
    float* ob = out + ((size_t)n * 1024 + (size_t)(2 * (h0 + wv) + (q >> 1))) * 1280
                    + (size_t)(2 * (cb + 4 * krow + u) + (q & 1));

    // one pixel-set (16 px) pipeline; fully independent per ps
    auto body = [&](int ps) __attribute__((always_inline)) -> float {
        const half8 c0 = bb0[ps * 16];
        const half8 c1 = bb1[ps * 16];
        const half8 c2 = bb2[ps * 16];
        // patch loads as float2 pairs (ds_read2_b32): issue early with c-frags
        const float2_t pt0a = *(const float2_t*)(pb0 + ps * 16);
        const float2_t pt0b = *(const float2_t*)(pb0 + ps * 16 + 2);
        const float2_t pt1a = *(const float2_t*)(pb1 + ps * 16);
        const float2_t pt1b = *(const float2_t*)(pb1 + ps * 16 + 2);
        const float2_t pt2a = *(const float2_t*)(pb2 + ps * 16);
        const float2_t pt2b = *(const float2_t*)(pb2 + ps * 16 + 2);
        const float pt0[4] = {pt0a[0], pt0a[1], pt0b[0], pt0b[1]};
        const float pt1[4] = {pt1a[0], pt1a[1], pt1b[0], pt1b[1]};
        const float pt2[4] = {pt2a[0], pt2a[1], pt2b[0], pt2b[1]};

        float4_t acc1 = zero4;
        acc1 = __builtin_amdgcn_mfma_f32_16x16x32_f16(a1[0], c0, acc1, 0, 0, 0);
        acc1 = __builtin_amdgcn_mfma_f32_16x16x32_f16(a1[1], c1, acc1, 0, 0, 0);
        acc1 = __builtin_amdgcn_mfma_f32_16x16x32_f16(a1[2], c2, acc1, 0, 0, 0);

        union { half8 v; fp16x2 h2[4]; uint32_t u32[4]; } a2;
        a2.h2[0] = __builtin_amdgcn_cvt_pkrtz(fmaxf(acc1[0] + b1q[0], 0.0f),
                                              fmaxf(acc1[1] + b1q[1], 0.0f));
        a2.h2[1] = __builtin_amdgcn_cvt_pkrtz(fmaxf(acc1[2] + b1q[2], 0.0f),
                                              fmaxf(acc1[3] + b1q[3], 0.0f));
        a2.u32[2] = (uint32_t)__shfl_xor((int)a2.u32[0], 16);
        a2.u32[3] = (uint32_t)__shfl_xor((int)a2.u32[1], 16);

        const float4_t d2_0 = __builtin_amdgcn_mfma_f32_16x16x32_f16(a2.v, b2f[0], zero4, 0, 0, 0);
        const float4_t d2_1 = __builtin_amdgcn_mfma_f32_16x16x32_f16(a2.v, b2f[1], zero4, 0, 0, 0);
        const float4_t d2_2 = __builtin_amdgcn_mfma_f32_16x16x32_f16(a2.v, b2f[2], zero4, 0, 0, 0);

        float se[4], sp[4];
        #pragma unroll
        for (int r = 0; r < 4; ++r) {
            const float e0 = __builtin_amdgcn_exp2f(fmaf(d2_0[r], C, b2q[0]));
            const float e1 = __builtin_amdgcn_exp2f(fmaf(d2_1[r], C, b2q[1]));
            const float e2 = __builtin_amdgcn_exp2f(fmaf(d2_2[r], C, b2q[2]));
            se[r] = e0 + e1 + e2;
            sp[r] = e0 * pt0[r] + e1 * pt1[r] + e2 * pt2[r];
        }
        #pragma unroll
        for (int r = 0; r < 4; ++r) {
            se[r] = rr_add<ROR8>(rr_add<ROR4>(se[r]));
            sp[r] = rr_add<ROR8>(rr_add<ROR4>(sp[r]));
        }
        float res[4];
        #pragma unroll
        for (int r = 0; r < 4; ++r) res[r] = sp[r] * __builtin_amdgcn_rcpf(se[r]);
        const float v01 = (u & 1) ? res[1] : res[0];
        const float v23 = (u & 1) ? res[3] : res[2];
        return (u & 2) ? v23 : v01;
    };

    // ---- FULLY UNROLLED: 5 trips x two independent streams; compile-time
    // indices let the scheduler hoist ds_reads deep across bodies (no movs).
    #pragma unroll
    for (int pp = 0; pp < 5; ++pp) {
        const float vA = body(pp);
        const float vB = body(pp + 5);
        ob[pp * 32]       = vA;
        ob[(pp + 5) * 32] = vB;
    }
}

extern "C" void kernel_launch(void* const* d_in, const int* in_sizes, int n_in,
                              void* d_out, int out_size, void* d_ws, size_t ws_size,
                              hipStream_t stream) {
    (void)in_sizes; (void)n_in; (void)out_size; (void)d_ws; (void)ws_size;
    const float* depth = (const float*)d_in[0];
    const float* cv    = (const float*)d_in[1];
    const float* w1    = (const float*)d_in[2];
    const float* b1    = (const float*)d_in[3];
    const float* w2    = (const float*)d_in[4];
    const float* b2    = (const float*)d_in[5];
    float* out = (float*)d_out;

    dim3 grid(640 / SW, 512 / SH, 4);   // (4, 128, 4) = 2048 blocks
    dim3 block(256);
    hipLaunchKernelGGL(depth_up_fused, grid, block, 0, stream,
                       depth, cv, w1, b1, w2, b2, out);
}

// Round 18
// 44.709 us; speedup vs baseline: 1.5821x; 1.5821x over previous
//
#include <hip/hip_runtime.h>

typedef _Float16 half8  __attribute__((ext_vector_type(8)));
typedef __fp16   fp16x2 __attribute__((ext_vector_type(2)));
typedef float    float4_t __attribute__((ext_vector_type(4)));

#define SH 4
#define SW 160
#define CW (SW + 2)   // 162 staged cv cols
#define NR (SH + 2)   // 6 staged rows
#define DW (CW + 1)   // 163: depth LDS row stride

// VALU-pipe rotate-reduce within each 16-lane row: v += dpp_ror<N>(v)
template <int CTRL>
__device__ __forceinline__ float rr_add(float v) {
    const int i = __float_as_int(v);
    const int p = __builtin_amdgcn_update_dpp(i, i, CTRL, 0xF, 0xF, false);
    return v + __int_as_float(p);
}
#define ROR4 0x124
#define ROR8 0x128

__global__ __launch_bounds__(256, 4) void depth_up_fused(
    const float* __restrict__ depth,
    const float* __restrict__ cv,
    const float* __restrict__ w1,   // [8,8,3,3]
    const float* __restrict__ b1,   // [8]
    const float* __restrict__ w2,   // [36,8]
    const float* __restrict__ b2,   // [36]
    float* __restrict__ out)        // [N, 1024, 1280]
{
    const int H = 512, W = 640;
    const size_t HW = (size_t)H * W;
    const int n  = blockIdx.z;
    const int h0 = blockIdx.y * SH;
    const int cb = blockIdx.x * SW;
    const int tid  = threadIdx.x;
    const int lane = tid & 63;
    const int wv   = tid >> 6;       // wave = row within strip
    const int o    = lane & 15;
    const int krow = lane >> 4;
    const int u    = o >> 2;         // tap-group
    const int q    = o & 3;          // softmax column

    __shared__ half8 s_cv[NR * CW];  // 15,552 B
    __shared__ float s_d[NR * DW];   //  3,912 B

    const float* __restrict__ cvn = cv + (size_t)n * 8 * HW;
    const float* __restrict__ dn  = depth + (size_t)n * HW;

    // ---- stage cv (fp16x8) + depth: branchless, 972 items padded to 1024 ----
    #pragma unroll
    for (int j = 0; j < 4; ++j) {
        const int i0 = tid + 256 * j;
        const int it = i0 < (NR * CW - 1) ? i0 : (NR * CW - 1);
        const int r  = it / CW;
        const int c  = it - r * CW;
        const int gh = h0 + r - 1;
        const int gw = cb + c - 1;
        const int ghs = gh < 0 ? 0 : (gh > H - 1 ? H - 1 : gh);
        const int gws = gw < 0 ? 0 : (gw > W - 1 ? W - 1 : gw);
        const bool ok = (gh == ghs) & (gw == gws);
        const float* p = cvn + (size_t)ghs * W + gws;
        float f[9];
        #pragma unroll
        for (int ch = 0; ch < 8; ++ch) f[ch] = p[(size_t)ch * HW];
        f[8] = dn[(size_t)ghs * W + gws];
        #pragma unroll
        for (int k = 0; k < 9; ++k) f[k] = ok ? f[k] : 0.0f;
        union { half8 v8; fp16x2 h2[4]; } hu;
        #pragma unroll
        for (int pq = 0; pq < 4; ++pq)
            hu.h2[pq] = __builtin_amdgcn_cvt_pkrtz(f[2 * pq], f[2 * pq + 1]);
        s_cv[r * CW + c] = hu.v8;
        s_d[r * DW + c]  = f[8];
    }

    // ---- conv1 weights as A-fragments: A1[row=och][k], k = tap*8 + c ----
    half8 a1[3];
    #pragma unroll
    for (int ki = 0; ki < 3; ++ki) {
        const int tap = 4 * ki + krow;
        #pragma unroll
        for (int j = 0; j < 8; ++j)
            a1[ki][j] = (tap < 9 && o < 8) ? (_Float16)w1[(o * 8 + j) * 9 + tap]
                                           : (_Float16)0.0f;
    }
    // cv B-fragment per-lane base byte offsets
    int aoff[3];
    #pragma unroll
    for (int ki = 0; ki < 3; ++ki) {
        const int tap0 = 4 * ki + krow;
        const int tap  = tap0 > 8 ? 8 : tap0;
        const int ky   = tap / 3;
        const int kx   = tap - 3 * ky;
        aoff[ki] = ((wv + ky) * CW + o + kx) * 16;
    }
    // b1 for this lane's 4 och (valid for krow<2; others unused junk)
    const float4_t b1q = *reinterpret_cast<const float4_t*>(b1 + (krow & 1) * 4);

    // ---- conv2 weights as B-fragments (only k=0..7 rows live -> krow==0) ----
    half8 b2f[3] = {};
    if (krow == 0) {
        #pragma unroll
        for (int t = 0; t < 3; ++t) {
            const int m = (o + 16 * t) > 35 ? 35 : (o + 16 * t);
            const float4_t wlo = *reinterpret_cast<const float4_t*>(w2 + m * 8);
            const float4_t whi = *reinterpret_cast<const float4_t*>(w2 + m * 8 + 4);
            #pragma unroll
            for (int j = 0; j < 4; ++j) {
                b2f[t][j]     = (_Float16)wlo[j];
                b2f[t][4 + j] = (_Float16)whi[j];
            }
        }
    }
    // 0.25 * log2(e) folded scale; bias pre-scaled into log2 domain.
    const float C = 0.25f * 1.44269504f;
    float b2q[3];
    #pragma unroll
    for (int t = 0; t < 3; ++t) {
        const int m = (o + 16 * t) > 35 ? 35 : (o + 16 * t);
        b2q[t] = C * b2[m];
    }
    if (u != 0) b2q[2] = -1.0e38f;   // exp2 -> 0 for the invalid tap

    // patch tap byte-offsets in s_d (lane-constant): taps {u, u+4, 8}
    int poff[3];
    {
        const int taps[3] = {u, u + 4, 8};
        #pragma unroll
        for (int t = 0; t < 3; ++t) {
            const int ky = taps[t] / 3;
            const int kx = taps[t] - 3 * ky;
            poff[t] = ((wv + ky) * DW + kx) * 4;
        }
    }

    __syncthreads();

    const char* cvb = (const char*)s_cv;
    const char* sdb = (const char*)s_d;
    const float4_t zero4 = {0.0f, 0.0f, 0.0f, 0.0f};

    const half8* bb0 = (const half8*)(cvb + aoff[0]);
    const half8* bb1 = (const half8*)(cvb + aoff[1]);
    const half8* bb2 = (const half8*)(cvb + aoff[2]);
    const float* pb0 = (const float*)(sdb + poff[0] + krow * 16);
    const float* pb1 = (const float*)(sdb + poff[1] + krow * 16);
    const float* pb2 = (const float*)(sdb + poff[2] + krow * 16);
    float* ob = out + ((size_t)n * 1024 + (size_t)(2 * (h0 + wv) + (q >> 1))) * 1280
                    + (size_t)(2 * (cb + 4 * krow + u) + (q & 1));

    // one pixel-set (16 px) pipeline; fully independent per ps
    auto body = [&](int ps) __attribute__((always_inline)) -> float {
        const half8 c0 = bb0[ps * 16];
        const half8 c1 = bb1[ps * 16];
        const half8 c2 = bb2[ps * 16];

        float4_t acc1 = zero4;
        acc1 = __builtin_amdgcn_mfma_f32_16x16x32_f16(a1[0], c0, acc1, 0, 0, 0);
        acc1 = __builtin_amdgcn_mfma_f32_16x16x32_f16(a1[1], c1, acc1, 0, 0, 0);
        acc1 = __builtin_amdgcn_mfma_f32_16x16x32_f16(a1[2], c2, acc1, 0, 0, 0);

        union { half8 v; fp16x2 h2[4]; uint32_t u32[4]; } a2;
        const float x0 = fmaxf(acc1[0] + b1q[0], 0.0f);
        const float x1 = fmaxf(acc1[1] + b1q[1], 0.0f);
        const float x2 = fmaxf(acc1[2] + b1q[2], 0.0f);
        const float x3 = fmaxf(acc1[3] + b1q[3], 0.0f);
        a2.h2[0] = __builtin_amdgcn_cvt_pkrtz(x0, x1);
        a2.h2[1] = __builtin_amdgcn_cvt_pkrtz(x2, x3);
        a2.u32[2] = (uint32_t)__shfl_xor((int)a2.u32[0], 16);
        a2.u32[3] = (uint32_t)__shfl_xor((int)a2.u32[1], 16);

        const float4_t d2_0 = __builtin_amdgcn_mfma_f32_16x16x32_f16(a2.v, b2f[0], zero4, 0, 0, 0);
        const float4_t d2_1 = __builtin_amdgcn_mfma_f32_16x16x32_f16(a2.v, b2f[1], zero4, 0, 0, 0);
        const float4_t d2_2 = __builtin_amdgcn_mfma_f32_16x16x32_f16(a2.v, b2f[2], zero4, 0, 0, 0);

        float se[4], sp[4];
        #pragma unroll
        for (int r = 0; r < 4; ++r) {
            const float e0 = __builtin_amdgcn_exp2f(fmaf(d2_0[r], C, b2q[0]));
            const float e1 = __builtin_amdgcn_exp2f(fmaf(d2_1[r], C, b2q[1]));
            const float e2 = __builtin_amdgcn_exp2f(fmaf(d2_2[r], C, b2q[2]));
            const float pt0 = pb0[ps * 16 + r];
            const float pt1 = pb1[ps * 16 + r];
            const float pt2 = pb2[ps * 16 + r];
            se[r] = e0 + e1 + e2;
            sp[r] = e0 * pt0 + e1 * pt1 + e2 * pt2;
        }
        #pragma unroll
        for (int r = 0; r < 4; ++r) {
            se[r] = rr_add<ROR8>(rr_add<ROR4>(se[r]));
            sp[r] = rr_add<ROR8>(rr_add<ROR4>(sp[r]));
        }
        float res[4];
        #pragma unroll
        for (int r = 0; r < 4; ++r) res[r] = sp[r] * __builtin_amdgcn_rcpf(se[r]);
        const float v01 = (u & 1) ? res[1] : res[0];
        const float v23 = (u & 1) ? res[3] : res[2];
        return (u & 2) ? v23 : v01;
    };

    // ---- 5 trips, two independent streams (ps, ps+5) per trip ----
    for (int pp = 0; pp < 5; ++pp) {
        const float vA = body(pp);
        const float vB = body(pp + 5);
        ob[pp * 32]       = vA;
        ob[(pp + 5) * 32] = vB;
    }
}

extern "C" void kernel_launch(void* const* d_in, const int* in_sizes, int n_in,
                              void* d_out, int out_size, void* d_ws, size_t ws_size,
                              hipStream_t stream) {
    (void)in_sizes; (void)n_in; (void)out_size; (void)d_ws; (void)ws_size;
    const float* depth = (const float*)d_in[0];
    const float* cv    = (const float*)d_in[1];
    const float* w1    = (const float*)d_in[2];
    const float* b1    = (const float*)d_in[3];
    const float* w2    = (const float*)d_in[4];
    const float* b2    = (const float*)d_in[5];
    float* out = (float*)d_out;

    dim3 grid(640 / SW, 512 / SH, 4);   // (4, 128, 4) = 2048 blocks
    dim3 block(256);
    hipLaunchKernelGGL(depth_up_fused, grid, block, 0, stream,
                       depth, cv, w1, b1, w2, b2, out);
}